// Round 10
// baseline (2424.609 us; speedup 1.0000x reference)
//
#include <hip/hip_runtime.h>
#include <hip/hip_bf16.h>

// VanillaRNN on MI355X — persistent cooperative kernel, XCD-local h exchange, v6.
// h_t = tanh(x_t @ W_hx^T + h_{t-1} @ W_hh^T + b_hx + b_hh)  (hh term skipped at t=0)
// out = h_last @ W_out^T + b_out
//
// grp = XCC_ID (32 batch rows), slot = per-XCD atomic (64 hidden cols).
// Wave kh (0..7) owns K-slice [kh*256,+256) of the block's [32 rows x 64 cols].
// Budget constraints learned R5-R9: 512-thr kernels capped at 128 VGPR (design
// live set <= ~110, else scratch spill); dynamic LDS must be <= 131072 (160 KB
// crashes); LDS W layout must be 256B rows + (col&7)<<4 XOR (else conflicts).
// v6: waves 0-5 hold K-local [0,128) in LDS (96 KB); streamed remainder via
// ordered asm loads with exact counted vmcnt, <=12 loads (48 regs) in flight.

#define BB 256
#define SS 128
#define II 512
#define HH 2048
#define OO 10

#define NTHR 512
#define NBLK 256
#define LDS_W   98304                    // waves 0..5 * 16 KB ([64 cols][128 K] bf16)
#define LDS_RED 32768                    // 4 regions * 8 KB (reused stage A/B)
#define LDS_BYTES (LDS_W + LDS_RED)      // 131072 (proven launchable; 160K crashes)

typedef __attribute__((ext_vector_type(8))) __bf16 bf16x8;
typedef __attribute__((ext_vector_type(4))) __bf16 bf16x4;
typedef __attribute__((ext_vector_type(4))) float f32x4;
typedef unsigned long long u64;

__device__ __forceinline__ f32x4 mfma_(bf16x8 a, bf16x8 b, f32x4 c) {
    return __builtin_amdgcn_mfma_f32_16x16x32_bf16(a, b, c, 0, 0, 0);
}

__global__ __launch_bounds__(256) void cvt_f32_bf16(const float* __restrict__ in,
                                                    __bf16* __restrict__ out, int n4) {
    int stride = gridDim.x * blockDim.x;
    for (int i = blockIdx.x * blockDim.x + threadIdx.x; i < n4; i += stride) {
        float4 v = reinterpret_cast<const float4*>(in)[i];
        bf16x4 o;
        o[0] = (__bf16)v.x; o[1] = (__bf16)v.y; o[2] = (__bf16)v.z; o[3] = (__bf16)v.w;
        *reinterpret_cast<bf16x4*>(out + 4 * (size_t)i) = o;
    }
}

#define AGLD(p) __hip_atomic_load((p), __ATOMIC_RELAXED, __HIP_MEMORY_SCOPE_AGENT)

// LDH: sc0 (L1-bypass, agent-coherent, hits dirty same-XCD L2). LDW: plain cached.
#define LDH(dst, base, off)                                                     \
    asm volatile("global_load_dwordx4 %0, %1, off offset:" #off " sc0"          \
                 : "=&v"(dst) : "v"(base));
#define LDW(dst, base, off)                                                     \
    asm volatile("global_load_dwordx4 %0, %1, off offset:" #off                 \
                 : "=&v"(dst) : "v"(base));

#define WAITN(n)                                                                \
    asm volatile("s_waitcnt vmcnt(" #n ")" ::: "memory");                       \
    __builtin_amdgcn_sched_barrier(0);

// 8 MFMAs: 4 col-frags x 2 row-frags for one 32-K chunk.
#define MFMA8(W0, W1, W2, W3, HA, HB)                                           \
    acc[0][0] = mfma_(W0, HA, acc[0][0]); acc[0][1] = mfma_(W0, HB, acc[0][1]); \
    acc[1][0] = mfma_(W1, HA, acc[1][0]); acc[1][1] = mfma_(W1, HB, acc[1][1]); \
    acc[2][0] = mfma_(W2, HA, acc[2][0]); acc[2][1] = mfma_(W2, HB, acc[2][1]); \
    acc[3][0] = mfma_(W3, HA, acc[3][0]); acc[3][1] = mfma_(W3, HB, acc[3][1]);

// One streamed chunk: 4 W frags + 2 h frags at byte offset OFF (6 loads).
#define CHUNK(W0, W1, W2, W3, HA, HB, OFF)                                      \
    LDW(W0, wpc0, OFF) LDW(W1, wpc1, OFF) LDW(W2, wpc2, OFF) LDW(W3, wpc3, OFF) \
    LDH(HA, p0, OFF)   LDH(HB, p1, OFF)

extern "C" __global__ void __launch_bounds__(NTHR, 1) rnn_persist(
    const __bf16* __restrict__ xbf,    // [B][S][I] bf16 prepacked
    const __bf16* __restrict__ Whh,    // [H][H] bf16 prepacked
    const __bf16* __restrict__ Whx,    // [H][I] bf16 prepacked
    const float*  __restrict__ bhx,    // [H]
    const float*  __restrict__ bhh,    // [H]
    __bf16* __restrict__ hb0,          // [B][H] ping
    __bf16* __restrict__ hb1,          // [B][H] pong
    unsigned* __restrict__ ctrs)       // [1024] zeroed: slot[g]=g*64, bar[g]=512+g*64
{
    extern __shared__ __align__(16) char lds[];
    const int tid = threadIdx.x;

    unsigned xcc;
    asm volatile("s_getreg_b32 %0, hwreg(HW_REG_XCC_ID)" : "=s"(xcc));
    const int grp = (int)(xcc & 7u);

    __shared__ unsigned slot_sh;
    if (tid == 0)
        slot_sh = __hip_atomic_fetch_add(ctrs + grp * 64, 1u, __ATOMIC_RELAXED,
                                         __HIP_MEMORY_SCOPE_AGENT);
    __syncthreads();
    const int slot = (int)(slot_sh & 31u);

    const int lane = tid & 63;
    const int kh   = tid >> 6;          // wave id 0..7 = K-slice [kh*256,+256)
    const int lq   = lane >> 4;         // 0..3
    const int lr   = lane & 15;
    const int colbase = slot * 64;      // hidden cols [colbase, +64)
    const int rowbase = grp * 32;       // batch rows  [rowbase, +32)

    // ---- waves 0..5: stage W_hh K-local [0,128) -> LDS (256B rows, XOR), once ----
    if (kh < 6) {
        const unsigned wb = (unsigned)kh * 16384u;
        for (int it = 0; it < 16; ++it) {
            const int f   = lane + it * 64;     // 0..1023
            const int col = f >> 4;             // 0..63
            const int u   = f & 15;             // 16B unit within 256B row
            bf16x8 v = *reinterpret_cast<const bf16x8*>(
                Whh + (size_t)(colbase + col) * HH + kh * 256 + u * 8);
            *reinterpret_cast<bf16x8*>(
                lds + ((wb + (unsigned)col * 256u + (unsigned)u * 16u)
                       ^ ((unsigned)(col & 7) << 4))) = v;
        }
    }
    // LDS A-frag read: col = cf*16+lr, k-local = kc*32+lq*8 (m214-verified pattern).
    const unsigned wswz  = (unsigned)(lr & 7) << 4;
    const unsigned abase = (unsigned)kh * 16384u + (unsigned)lr * 256u + (unsigned)lq * 16u;
#define LDSA(cf, kc)                                                            \
    (*reinterpret_cast<const bf16x8*>(                                          \
        lds + ((abase + (unsigned)(cf) * 4096u + (unsigned)(kc) * 64u) ^ wswz)))

    const int ecol0 = colbase + (kh & 3) * 16 + 4 * lq;   // epilogue cols (kh<4)
    unsigned* bar = ctrs + 512 + grp * 64;
    float* red = reinterpret_cast<float*>(lds + LDS_W);

    // Stream-W bases at this wave's K-slice start (k-local 0), one per cf.
    const char* wpc0 = (const char*)(Whh + (size_t)(colbase + lr) * HH + kh * 256 + lq * 8);
    const char* wpc1 = wpc0 + (size_t)16 * HH * 2;
    const char* wpc2 = wpc0 + (size_t)32 * HH * 2;
    const char* wpc3 = wpc0 + (size_t)48 * HH * 2;

    __syncthreads();   // W staging complete

    for (int s = 0; s < SS - 1; ++s) {
        const __bf16* hrd = (s & 1) ? hb0 : hb1;
        __bf16*       hwr = (s & 1) ? hb1 : hb0;

        f32x4 acc[4][2] = {};   // [cf][rf]

        // ---- x-projection, K=512 split 8 ways (64/wave); overlaps barrier skew ----
#pragma unroll
        for (int kc = 0; kc < 2; ++kc) {
            bf16x8 wxf[4], xf[2];
#pragma unroll
            for (int cf = 0; cf < 4; ++cf)
                wxf[cf] = *reinterpret_cast<const bf16x8*>(
                    Whx + (size_t)(colbase + cf * 16 + lr) * II + kh * 64 + kc * 32 + lq * 8);
#pragma unroll
            for (int rf = 0; rf < 2; ++rf)
                xf[rf] = *reinterpret_cast<const bf16x8*>(
                    xbf + (size_t)(rowbase + rf * 16 + lr) * (SS * II)
                    + (size_t)s * II + kh * 64 + kc * 32 + lq * 8);
            MFMA8(wxf[0], wxf[1], wxf[2], wxf[3], xf[0], xf[1])
        }

        if (s > 0) {
            // ---- per-XCD barrier wait (arrivals of step s-1) ----
            if (tid == 0) {
                const unsigned target = (unsigned)s * 32u;
                unsigned polls = 0;
                while (AGLD(bar) < target) {
                    __builtin_amdgcn_s_sleep(1);
                    if (++polls > (1u << 20)) break;   // no-hang safety valve
                }
            }
            __syncthreads();

            const char* p0 = (const char*)(hrd + (size_t)(rowbase + lr) * HH + kh * 256 + lq * 8);
            const char* p1 = (const char*)(hrd + (size_t)(rowbase + 16 + lr) * HH + kh * 256 + lq * 8);

            if (kh < 6) {
                // LDS holds k-local [0,128) (kc 0-3); stream kc 4-7 (offsets 256..448).
                bf16x8 wA0, wA1, wA2, wA3, wB0, wB1, wB2, wB3;
                bf16x8 ha0, ha1, hq0, hq1, hc0, hc1, hd0, hd1;
                WAITN(0)   // drain x loads: exact vmcnt baseline
                CHUNK(wA0, wA1, wA2, wA3, ha0, ha1, 256)   //  6 out (kc4)
                CHUNK(wB0, wB1, wB2, wB3, hq0, hq1, 320)   // 12 out (kc5)
                WAITN(6)   // kc4 ready
                MFMA8(wA0, wA1, wA2, wA3, ha0, ha1)
                CHUNK(wA0, wA1, wA2, wA3, hc0, hc1, 384)   // 12 out (kc6)
                WAITN(6)   // kc5 ready
                MFMA8(wB0, wB1, wB2, wB3, hq0, hq1)
                CHUNK(wB0, wB1, wB2, wB3, hd0, hd1, 448)   // 12 out (kc7)
                WAITN(6)   // kc6 ready
                MFMA8(wA0, wA1, wA2, wA3, hc0, hc1)
                LDH(ha0, p0, 0)   LDH(ha1, p1, 0)
                LDH(hq0, p0, 64)  LDH(hq1, p1, 64)         // 10 out
                WAITN(4)   // kc7 ready
                MFMA8(wB0, wB1, wB2, wB3, hd0, hd1)
                LDH(hc0, p0, 128) LDH(hc1, p1, 128)
                LDH(hd0, p0, 192) LDH(hd1, p1, 192)        //  8 out
                WAITN(4)   // h kc0,kc1 ready
                {
                    bf16x8 a0 = LDSA(0, 0), a1 = LDSA(1, 0), a2 = LDSA(2, 0), a3 = LDSA(3, 0);
                    MFMA8(a0, a1, a2, a3, ha0, ha1)
                    a0 = LDSA(0, 1); a1 = LDSA(1, 1); a2 = LDSA(2, 1); a3 = LDSA(3, 1);
                    MFMA8(a0, a1, a2, a3, hq0, hq1)
                }
                WAITN(0)   // h kc2,kc3 ready
                {
                    bf16x8 a0 = LDSA(0, 2), a1 = LDSA(1, 2), a2 = LDSA(2, 2), a3 = LDSA(3, 2);
                    MFMA8(a0, a1, a2, a3, hc0, hc1)
                    a0 = LDSA(0, 3); a1 = LDSA(1, 3); a2 = LDSA(2, 3); a3 = LDSA(3, 3);
                    MFMA8(a0, a1, a2, a3, hd0, hd1)
                }
            } else {
                // Waves 6,7: stream all 8 chunks (offsets 0..448), 2-buffer pipeline.
                bf16x8 wA0, wA1, wA2, wA3, wB0, wB1, wB2, wB3;
                bf16x8 ha0, ha1, hq0, hq1;
                WAITN(0)
                CHUNK(wA0, wA1, wA2, wA3, ha0, ha1, 0)     //  6 out
                CHUNK(wB0, wB1, wB2, wB3, hq0, hq1, 64)    // 12 out
                WAITN(6) MFMA8(wA0, wA1, wA2, wA3, ha0, ha1)
                CHUNK(wA0, wA1, wA2, wA3, ha0, ha1, 128)
                WAITN(6) MFMA8(wB0, wB1, wB2, wB3, hq0, hq1)
                CHUNK(wB0, wB1, wB2, wB3, hq0, hq1, 192)
                WAITN(6) MFMA8(wA0, wA1, wA2, wA3, ha0, ha1)
                CHUNK(wA0, wA1, wA2, wA3, ha0, ha1, 256)
                WAITN(6) MFMA8(wB0, wB1, wB2, wB3, hq0, hq1)
                CHUNK(wB0, wB1, wB2, wB3, hq0, hq1, 320)
                WAITN(6) MFMA8(wA0, wA1, wA2, wA3, ha0, ha1)
                CHUNK(wA0, wA1, wA2, wA3, ha0, ha1, 384)
                WAITN(6) MFMA8(wB0, wB1, wB2, wB3, hq0, hq1)
                CHUNK(wB0, wB1, wB2, wB3, hq0, hq1, 448)
                WAITN(6) MFMA8(wA0, wA1, wA2, wA3, ha0, ha1)
                WAITN(0) MFMA8(wB0, wB1, wB2, wB3, hq0, hq1)
            }
        }

        // ---- stage A: waves 4..7 -> red regions 0..3 ([j][lane] f32x4) ----
        if (kh >= 4) {
            char* base = (char*)red + (size_t)(kh - 4) * 8192 + (size_t)lane * 16;
#pragma unroll
            for (int cf = 0; cf < 4; ++cf)
#pragma unroll
                for (int rf = 0; rf < 2; ++rf)
                    *reinterpret_cast<f32x4*>(base + (cf * 2 + rf) * 1024) = acc[cf][rf];
        }
        __syncthreads();
        if (kh < 4) {
            char* base = (char*)red + (size_t)kh * 8192 + (size_t)lane * 16;
#pragma unroll
            for (int cf = 0; cf < 4; ++cf)
#pragma unroll
                for (int rf = 0; rf < 2; ++rf)
                    acc[cf][rf] += *reinterpret_cast<const f32x4*>(base + (cf * 2 + rf) * 1024);
            // ---- stage B (reuse same region): give away cf != kh slices ----
#pragma unroll
            for (int cf = 0; cf < 4; ++cf)
                if (cf != kh)
#pragma unroll
                    for (int rf = 0; rf < 2; ++rf)
                        *reinterpret_cast<f32x4*>(base + (cf * 2 + rf) * 1024) = acc[cf][rf];
        }
        __syncthreads();
        if (kh < 4) {
            // ---- collect partners' cf == kh slices, epilogue for 16 cols ----
#pragma unroll
            for (int p = 0; p < 4; ++p)
                if (p != kh) {
                    const char* pb = (const char*)red + (size_t)p * 8192 + (size_t)lane * 16;
#pragma unroll
                    for (int rf = 0; rf < 2; ++rf)
                        acc[kh][rf] += *reinterpret_cast<const f32x4*>(pb + (kh * 2 + rf) * 1024);
                }
            const float4 bx4 = *reinterpret_cast<const float4*>(bhx + ecol0);
            const float4 bh4 = *reinterpret_cast<const float4*>(bhh + ecol0);
#pragma unroll
            for (int rf = 0; rf < 2; ++rf) {
                union { unsigned short u[4]; u64 ll; } P;
#pragma unroll
                for (int e = 0; e < 4; ++e) {
                    const float bias = ((const float*)&bx4)[e] +
                                       (s > 0 ? ((const float*)&bh4)[e] : 0.0f);
                    __bf16 v = (__bf16)tanhf(acc[kh][rf][e] + bias);
                    P.u[e] = __builtin_bit_cast(unsigned short, v);
                }
                *reinterpret_cast<u64*>(
                    hwr + (size_t)(rowbase + rf * 16 + lr) * HH + ecol0) = P.ll;
            }
            asm volatile("s_waitcnt vmcnt(0)" ::: "memory");   // stores in L2
        }
        __syncthreads();   // SB2: all stores of this step complete
        if (s < SS - 2 && tid == 0)
            __hip_atomic_fetch_add(bar, 1u, __ATOMIC_RELAXED, __HIP_MEMORY_SCOPE_AGENT);
    }
#undef LDSA
}

// out[b][o] = sum_h h[b][h] * W_out[o][h] + b_out[o]; one block per batch row.
__global__ __launch_bounds__(256) void rnn_out(
    const __bf16* __restrict__ h, const float* __restrict__ W_out,
    const float* __restrict__ b_out, float* __restrict__ out)
{
    const int b = blockIdx.x;
    const int tid = threadIdx.x;
    __shared__ float red[OO][4];

    float hv[8];
#pragma unroll
    for (int e = 0; e < 8; ++e)
        hv[e] = (float)h[(size_t)b * HH + tid + e * 256];

#pragma unroll
    for (int o = 0; o < OO; ++o) {
        float s = 0.0f;
#pragma unroll
        for (int e = 0; e < 8; ++e)
            s += hv[e] * W_out[(size_t)o * HH + tid + e * 256];
        for (int off = 32; off; off >>= 1) s += __shfl_down(s, off);
        if ((tid & 63) == 0) red[o][tid >> 6] = s;
    }
    __syncthreads();
    if (tid < OO) {
        float s = red[tid][0] + red[tid][1] + red[tid][2] + red[tid][3];
        out[(size_t)b * OO + tid] = s + b_out[tid];
    }
}

extern "C" void kernel_launch(void* const* d_in, const int* in_sizes, int n_in,
                              void* d_out, int out_size, void* d_ws, size_t ws_size,
                              hipStream_t stream) {
    (void)in_sizes; (void)n_in; (void)out_size; (void)ws_size;

    const float* x     = (const float*)d_in[0];
    const float* W_hx  = (const float*)d_in[1];
    const float* b_hx  = (const float*)d_in[2];
    const float* W_hh  = (const float*)d_in[3];
    const float* b_hh  = (const float*)d_in[4];
    const float* W_out = (const float*)d_in[5];
    const float* b_out = (const float*)d_in[6];
    float* out = (float*)d_out;

    char* ws = (char*)d_ws;
    __bf16*   hb0    = (__bf16*)ws;                                   // 1 MB
    __bf16*   hb1    = hb0 + (size_t)BB * HH;                         // 1 MB
    unsigned* ctrs   = (unsigned*)(ws + 2 * (size_t)BB * HH * 2);     // 4 KB
    __bf16*   Whh_bf = (__bf16*)(ws + 2 * (size_t)BB * HH * 2 + 4096);// 8 MB
    __bf16*   Whx_bf = Whh_bf + (size_t)HH * HH;                      // 2 MB
    __bf16*   xbf    = Whx_bf + (size_t)HH * II;                      // 33.6 MB

    hipMemsetAsync(ctrs, 0, 4096, stream);
    cvt_f32_bf16<<<1024, 256, 0, stream>>>(W_hh, Whh_bf, HH * HH / 4);
    cvt_f32_bf16<<<512, 256, 0, stream>>>(W_hx, Whx_bf, HH * II / 4);
    cvt_f32_bf16<<<4096, 256, 0, stream>>>(x, xbf, BB * SS * II / 4);

    static bool attr_set = false;   // host-side one-time setup (same effect every call)
    if (!attr_set) {
        hipFuncSetAttribute(reinterpret_cast<const void*>(rnn_persist),
                            hipFuncAttributeMaxDynamicSharedMemorySize, LDS_BYTES);
        attr_set = true;
    }

    void* args[] = {(void*)&xbf, (void*)&Whh_bf, (void*)&Whx_bf, (void*)&b_hx,
                    (void*)&b_hh, (void*)&hb0, (void*)&hb1, (void*)&ctrs};
    hipError_t e = hipLaunchCooperativeKernel(
        reinterpret_cast<const void*>(rnn_persist),
        dim3(NBLK), dim3(NTHR), args, LDS_BYTES, stream);
    if (e != hipSuccess) {
        // Fallback: plain launch. 128 KB LDS -> 1 block/CU, grid == CU count,
        // so all blocks co-resident; barrier spin has a timeout regardless.
        rnn_persist<<<dim3(NBLK), dim3(NTHR), LDS_BYTES, stream>>>(
            xbf, Whh_bf, Whx_bf, b_hx, b_hh, hb0, hb1, ctrs);
    }

    // 127 steps: step s writes (s&1)?hb1:hb0; s=126 (even) -> hb0 holds h_last.
    rnn_out<<<BB, 256, 0, stream>>>(hb0, W_out, b_out, out);
}